// Round 2
// baseline (380.111 us; speedup 1.0000x reference)
//
#include <hip/hip_runtime.h>
#include <math.h>

#define BB 4
#define CC 256
#define DD 32
#define NN 4096

typedef __attribute__((ext_vector_type(8))) short short8;
typedef __attribute__((ext_vector_type(4))) float floatx4;
typedef __attribute__((ext_vector_type(4))) int intx4;

#define SCALEF (0.17677669529663687f * 1.4426950408889634f)  // 1/sqrt(32)*log2(e)

// float -> bf16 round-to-nearest-even
__device__ __forceinline__ ushort f2bf(float f) {
    unsigned int u = __builtin_bit_cast(unsigned int, f);
    u += 0x7FFFu + ((u >> 16) & 1u);
    return (ushort)(u >> 16);
}
// pack two floats' bf16 truncations into one dword with a single v_perm_b32
__device__ __forceinline__ int pk_trunc(float a, float b) {
    return (int)__builtin_amdgcn_perm(__builtin_bit_cast(unsigned, b),
                                      __builtin_bit_cast(unsigned, a),
                                      0x07060302u);
}
__device__ __forceinline__ float fast_exp2(float x) {
#if __has_builtin(__builtin_amdgcn_exp2f)
    return __builtin_amdgcn_exp2f(x);
#else
    return exp2f(x);
#endif
}

// ---------------------------------------------------------------------------
// Kernel 0a: one-time weight conversion to bf16 (truncation — identical to the
// pk_trunc the GEMMs previously did inline, so numerics are unchanged).
// Wall[320][256] = [Wq*SCALEF ; Wk ; Wv], Wpb[256][256] = Wp.
// ---------------------------------------------------------------------------
__global__ __launch_bounds__(256) void prep_w(
    const float* __restrict__ Wq, const float* __restrict__ Wk,
    const float* __restrict__ Wv, const float* __restrict__ Wp,
    ushort* __restrict__ Wall, ushort* __restrict__ Wpb)
{
    const int e = (blockIdx.x * 256 + threadIdx.x) * 4;   // 144 blocks * 1024 = 576*256
    const int row = e >> 8, col = e & 255;
    const float* src;
    float s = 1.0f;
    ushort* dst;
    int drow;
    if (row < 32)       { src = Wq + (size_t)row * CC;          s = SCALEF; dst = Wall; drow = row; }
    else if (row < 64)  { src = Wk + (size_t)(row - 32) * CC;   dst = Wall; drow = row; }
    else if (row < 320) { src = Wv + (size_t)(row - 64) * CC;   dst = Wall; drow = row; }
    else                { src = Wp + (size_t)(row - 320) * CC;  dst = Wpb;  drow = row - 320; }
    const floatx4 w = *(const floatx4*)(src + col);
    int2 d;
    d.x = pk_trunc(w[0] * s, w[1] * s);
    d.y = pk_trunc(w[2] * s, w[3] * s);
    *(int2*)(dst + (size_t)drow * CC + col) = d;
}

// ---------------------------------------------------------------------------
// Kernel 0b: x (B,C,N) fp32 -> xT (B,N,C) bf16 (truncation), LDS 64x64 tile.
// ---------------------------------------------------------------------------
#define TP 66
__global__ __launch_bounds__(256) void prep_xt(
    const float* __restrict__ x, ushort* __restrict__ xT)
{
    __shared__ ushort tile[64 * TP];
    const int t = threadIdx.x;
    const int b = blockIdx.z;
    const int c0 = blockIdx.y * 64;
    const int n0 = blockIdx.x * 64;
    const int cl = (t >> 4) * 4;   // 0..60, 4 c-rows per thread
    const int nl = (t & 15) * 4;   // 0..60, 4 n-cols per thread

    const float* src = x + ((size_t)b * CC + c0 + cl) * NN + n0 + nl;
    floatx4 v[4];
    #pragma unroll
    for (int i = 0; i < 4; ++i) v[i] = *(const floatx4*)(src + (size_t)i * NN);

    #pragma unroll
    for (int j = 0; j < 4; ++j) {
        *(int*)&tile[(nl + j) * TP + cl]     = pk_trunc(v[0][j], v[1][j]);
        *(int*)&tile[(nl + j) * TP + cl + 2] = pk_trunc(v[2][j], v[3][j]);
    }
    __syncthreads();

    const int nr = t >> 2;            // 0..63
    const int coff = (t & 3) * 16;    // 0,16,32,48
    int r[8];
    #pragma unroll
    for (int u = 0; u < 8; ++u) r[u] = *(const int*)&tile[nr * TP + coff + u * 2];
    ushort* dst = xT + ((size_t)b * NN + n0 + nr) * CC + c0 + coff;
    intx4 o0 = {r[0], r[1], r[2], r[3]};
    intx4 o1 = {r[4], r[5], r[6], r[7]};
    *(intx4*)dst = o0;
    *(intx4*)(dst + 8) = o1;
}

// ---------------------------------------------------------------------------
// Kernel 1: MFMA QKV projection v2 — pure bf16 short8 loads (A from Wall,
// B from xT), 4 loads + 4 MFMA per k-step.
// ---------------------------------------------------------------------------
__global__ __launch_bounds__(256) void qkv_mfma(
    const ushort* __restrict__ xT, const ushort* __restrict__ Wall,
    const float* __restrict__ bq, const float* __restrict__ bk,
    const float* __restrict__ bv,
    ushort* __restrict__ qb, ushort* __restrict__ kb, ushort* __restrict__ vb)
{
    const int t = threadIdx.x;
    const int wave = t >> 6;
    const int lane = t & 63;
    const int l15 = lane & 15, qd = lane >> 4;
    const int b = blockIdx.z, mt = blockIdx.y;   // mt 0..9
    const int n0 = blockIdx.x * 128 + wave * 32;

    const ushort* arow = Wall + (size_t)(mt * 32 + l15) * CC + qd * 8;
    const ushort* brow = xT + ((size_t)b * NN + n0 + l15) * CC + qd * 8;

    floatx4 z = {0.f, 0.f, 0.f, 0.f};
    floatx4 acc[2][2];
    acc[0][0] = z; acc[0][1] = z; acc[1][0] = z; acc[1][1] = z;

    #pragma unroll
    for (int k0 = 0; k0 < CC; k0 += 32) {
        short8 af[2], bfr[2];
        af[0]  = *(const short8*)(arow + k0);
        af[1]  = *(const short8*)(arow + 16 * CC + k0);
        bfr[0] = *(const short8*)(brow + k0);
        bfr[1] = *(const short8*)(brow + 16 * CC + k0);
        #pragma unroll
        for (int fm = 0; fm < 2; ++fm)
            #pragma unroll
            for (int fn = 0; fn < 2; ++fn)
                acc[fm][fn] = __builtin_amdgcn_mfma_f32_16x16x32_bf16(af[fm], bfr[fn], acc[fm][fn], 0, 0, 0);
    }

    #pragma unroll
    for (int fm = 0; fm < 2; ++fm) {
        const int o0 = fm * 16 + qd * 4;
        if (mt == 0) {
            const floatx4 bb = *(const floatx4*)(bq + o0);
            #pragma unroll
            for (int fn = 0; fn < 2; ++fn) {
                ushort4 h;
                h.x = f2bf(acc[fm][fn][0] + bb[0] * SCALEF);
                h.y = f2bf(acc[fm][fn][1] + bb[1] * SCALEF);
                h.z = f2bf(acc[fm][fn][2] + bb[2] * SCALEF);
                h.w = f2bf(acc[fm][fn][3] + bb[3] * SCALEF);
                *(ushort4*)(qb + ((size_t)b * NN + n0 + fn * 16 + l15) * DD + o0) = h;
            }
        } else if (mt == 1) {
            const floatx4 bb = *(const floatx4*)(bk + o0);
            #pragma unroll
            for (int fn = 0; fn < 2; ++fn) {
                ushort4 h;
                h.x = f2bf(acc[fm][fn][0] + bb[0]);
                h.y = f2bf(acc[fm][fn][1] + bb[1]);
                h.z = f2bf(acc[fm][fn][2] + bb[2]);
                h.w = f2bf(acc[fm][fn][3] + bb[3]);
                *(ushort4*)(kb + ((size_t)b * NN + n0 + fn * 16 + l15) * DD + o0) = h;
            }
        } else {
            const int oc = (mt - 2) * 32 + o0;
            const floatx4 bb = *(const floatx4*)(bv + oc);
            #pragma unroll
            for (int r = 0; r < 4; ++r)
                #pragma unroll
                for (int fn = 0; fn < 2; ++fn)
                    vb[((size_t)b * CC + oc + r) * NN + n0 + fn * 16 + l15] = f2bf(acc[fm][fn][r] + bb[r]);
        }
    }
}

// ---------------------------------------------------------------------------
// Kernel 2: MFMA flash attention v3 — LDS-shared P across ALL 256 channels.
// Block = one 64-q tile x 256 c x 4096 keys, 8 waves (512 thr), grid (4b,64qt)
// = 256 blocks = 1/CU.  Per 32-key step:
//   wave w (f=w&3, h=w>>2) computes its QK^T piece mfma(K[h*16..],Q[f*16..]),
//   4 exp2 + 2 pk_trunc, writes 8B into the bf16 P buffer laid out in PV
//   B-frag order (index map = algebraic inverse of the proven R6 shfl
//   transpose), 1 barrier (double-buffered P), then every wave reads the full
//   P tile (4 x ds_read_b128) and runs 8 PV MFMA into its private 64q x 32c
//   slice (c0w = w*32).  l-sum: h==0 waves accumulate mfma(ones,pt[f]); shared
//   via 64-float LDS at the end.  Kills the 4x P recompute + all 32 shfls and
//   the 32KB O reduction tree of R6.
// ---------------------------------------------------------------------------
__global__ __launch_bounds__(512) void attn_mfma(
    const ushort* __restrict__ qb, const ushort* __restrict__ kb,
    const ushort* __restrict__ vb, ushort* __restrict__ aoT)
{
    __shared__ ushort ptb[2][4][512];   // [parity][f][lane*8] bf16 P in B-frag layout
    __shared__ float lred[64];

    const int t = threadIdx.x;
    const int w = t >> 6;                // wave 0..7
    const int lane = t & 63;
    const int l15 = lane & 15;
    const int qd = lane >> 4;
    const int f = w & 3;                 // q f-group this wave produces
    const int h = w >> 2;                // key 16-half this wave produces
    const int c0w = w * 32;              // this wave's private channel slice
    const int b = blockIdx.x;
    const int q0 = blockIdx.y * 64;

    // Q fragment for this wave's f-group (B-operand of QK^T)
    const short8 qf = *(const short8*)(qb + ((size_t)b * NN + q0 + f * 16 + l15) * DD + qd * 8);

    // K row pointer: keys h*16 + l15 within each 32-key step (A-operand rows)
    const ushort* krow = kb + ((size_t)b * NN + h * 16 + l15) * DD + qd * 8;
    // V row pointers: channels c0w + ct*16 + l15 (A-operand rows), keys along N
    const ushort* vrow = vb + ((size_t)b * CC + c0w + l15) * (size_t)NN + qd * 8;

    const short8 ones = {0x3F80, 0x3F80, 0x3F80, 0x3F80, 0x3F80, 0x3F80, 0x3F80, 0x3F80};
    floatx4 z = {0.f, 0.f, 0.f, 0.f};
    floatx4 acc[4][2];   // [f2][ct]: 64q x 32c private output slice
    floatx4 accl = z;    // l-sum for f-group f (h==0 waves only)
    #pragma unroll
    for (int f2 = 0; f2 < 4; ++f2) { acc[f2][0] = z; acc[f2][1] = z; }

    // write slot for this wave's P piece (inverse of the R6 shfl transpose):
    // dst lane = (2h + (qd>>1))*16 + l15, dword offset (qd&1)*2
    const int wlane = ((h * 2 + (qd >> 1)) << 4) | l15;
    const int woff = wlane * 8 + (qd & 1) * 4;   // in ushorts

    short8 kf  = *(const short8*)krow;
    short8 vf0 = *(const short8*)vrow;
    short8 vf1 = *(const short8*)(vrow + (size_t)16 * NN);

    for (int kt = 0; kt < 128; ++kt) {
        const int p = kt & 1;

        // QK^T piece: D[key h*16+qd*4+r][q f*16+l15]
        floatx4 s = __builtin_amdgcn_mfma_f32_16x16x32_bf16(kf, qf, z, 0, 0, 0);

        // prefetch next 32-key step (last iter overruns into adjacent ws — unused)
        krow += 32 * DD;
        vrow += 32;
        short8 kfn  = *(const short8*)krow;
        short8 vf0n = *(const short8*)vrow;
        short8 vf1n = *(const short8*)(vrow + (size_t)16 * NN);

        // softmax numerator (no max subtraction; Wq pre-scaled by 1/sqrt(32)*log2e)
        float e0 = fast_exp2(s[0]), e1 = fast_exp2(s[1]);
        float e2 = fast_exp2(s[2]), e3 = fast_exp2(s[3]);
        int2 pw;
        pw.x = pk_trunc(e0, e1);
        pw.y = pk_trunc(e2, e3);
        *(int2*)&ptb[p][f][woff] = pw;

        __syncthreads();

        short8 pt[4];
        #pragma unroll
        for (int f2 = 0; f2 < 4; ++f2)
            pt[f2] = *(const short8*)&ptb[p][f2][lane * 8];

        if (h == 0)
            accl = __builtin_amdgcn_mfma_f32_16x16x32_bf16(ones, pt[f], accl, 0, 0, 0);

        #pragma unroll
        for (int f2 = 0; f2 < 4; ++f2) {
            acc[f2][0] = __builtin_amdgcn_mfma_f32_16x16x32_bf16(vf0, pt[f2], acc[f2][0], 0, 0, 0);
            acc[f2][1] = __builtin_amdgcn_mfma_f32_16x16x32_bf16(vf1, pt[f2], acc[f2][1], 0, 0, 0);
        }

        kf = kfn; vf0 = vf0n; vf1 = vf1n;
    }

    // ---- share l-sums (64 q values) ----
    if (h == 0 && qd == 0) lred[f * 16 + l15] = accl[0];
    __syncthreads();

    #pragma unroll
    for (int f2 = 0; f2 < 4; ++f2) {
        const float inv = 1.0f / lred[f2 * 16 + l15];
        ushort* dst = aoT + ((size_t)b * NN + q0 + f2 * 16 + l15) * CC + c0w + qd * 4;
        #pragma unroll
        for (int ct = 0; ct < 2; ++ct) {
            ushort4 o;
            o.x = f2bf(acc[f2][ct][0] * inv);
            o.y = f2bf(acc[f2][ct][1] * inv);
            o.z = f2bf(acc[f2][ct][2] * inv);
            o.w = f2bf(acc[f2][ct][3] * inv);
            *(ushort4*)(dst + ct * 16) = o;
        }
    }
}

// ---------------------------------------------------------------------------
// Kernel 3: MFMA output projection + residual v2.
// ---------------------------------------------------------------------------
__global__ __launch_bounds__(256) void proj_mfma(
    const ushort* __restrict__ aoT, const ushort* __restrict__ Wpb,
    const float* __restrict__ bp, const float* __restrict__ x,
    const float* __restrict__ gamma, float* __restrict__ out)
{
    const int t = threadIdx.x;
    const int wave = t >> 6;
    const int lane = t & 63;
    const int l15 = lane & 15;
    const int qd = lane >> 4;
    const int b = blockIdx.z;
    const int m0 = blockIdx.y * 32;
    const int n0 = blockIdx.x * 128 + wave * 32;

    floatx4 z = {0.f, 0.f, 0.f, 0.f};
    floatx4 acc[2][2];   // [fm][fn]
    acc[0][0] = z; acc[0][1] = z; acc[1][0] = z; acc[1][1] = z;

    const ushort* arow = aoT + ((size_t)b * NN + n0 + l15) * CC + qd * 8;
    const ushort* wrow = Wpb + (size_t)(m0 + l15) * CC + qd * 8;

    #pragma unroll
    for (int k0 = 0; k0 < CC; k0 += 32) {
        short8 af[2], bfr[2];
        af[0]  = *(const short8*)(wrow + k0);
        af[1]  = *(const short8*)(wrow + 16 * CC + k0);
        bfr[0] = *(const short8*)(arow + k0);
        bfr[1] = *(const short8*)(arow + 16 * CC + k0);
        #pragma unroll
        for (int fm = 0; fm < 2; ++fm)
            #pragma unroll
            for (int fn = 0; fn < 2; ++fn)
                acc[fm][fn] = __builtin_amdgcn_mfma_f32_16x16x32_bf16(af[fm], bfr[fn], acc[fm][fn], 0, 0, 0);
    }

    const float g = gamma[0];
    #pragma unroll
    for (int fm = 0; fm < 2; ++fm) {
        #pragma unroll
        for (int r = 0; r < 4; ++r) {
            int m = m0 + fm * 16 + qd * 4 + r;
            float bpv = bp[m];
            #pragma unroll
            for (int fn = 0; fn < 2; ++fn) {
                size_t addr = ((size_t)b * CC + m) * NN + n0 + fn * 16 + l15;
                out[addr] = fmaf(g, acc[fm][fn][r] + bpv, x[addr]);
            }
        }
    }
}

extern "C" void kernel_launch(void* const* d_in, const int* in_sizes, int n_in,
                              void* d_out, int out_size, void* d_ws, size_t ws_size,
                              hipStream_t stream)
{
    const float* x     = (const float*)d_in[0];
    const float* Wq    = (const float*)d_in[1];
    const float* bq    = (const float*)d_in[2];
    const float* Wk    = (const float*)d_in[3];
    const float* bk    = (const float*)d_in[4];
    const float* Wv    = (const float*)d_in[5];
    const float* bv    = (const float*)d_in[6];
    const float* Wp    = (const float*)d_in[7];
    const float* bp    = (const float*)d_in[8];
    const float* gamma = (const float*)d_in[9];
    float* out = (float*)d_out;

    ushort* qbw  = (ushort*)d_ws;                        // B*N*32  bf16 = 1 MB
    ushort* kbw  = qbw + (size_t)BB * NN * DD;           // B*N*32  bf16 = 1 MB
    ushort* vbw  = kbw + (size_t)BB * NN * DD;           // B*C*N   bf16 = 8 MB
    ushort* xaoT = vbw + (size_t)BB * CC * NN;           // xT during qkv, aoT after attn (8 MB, aliased)
    ushort* Wall = xaoT + (size_t)BB * NN * CC;          // 320*256 bf16 = 160 KB
    ushort* Wpb  = Wall + (size_t)320 * CC;              // 256*256 bf16 = 128 KB

    prep_w<<<dim3(144), 256, 0, stream>>>(Wq, Wk, Wv, Wp, Wall, Wpb);
    prep_xt<<<dim3(NN / 64, CC / 64, BB), 256, 0, stream>>>(x, xaoT);
    qkv_mfma<<<dim3(NN / 128, 10, BB), 256, 0, stream>>>(xaoT, Wall, bq, bk, bv, qbw, kbw, vbw);
    attn_mfma<<<dim3(BB, NN / 64), 512, 0, stream>>>(qbw, kbw, vbw, xaoT);
    proj_mfma<<<dim3(NN / 128, CC / 32, BB), 256, 0, stream>>>(xaoT, Wpb, bp, x, gamma, out);
}

// Round 5
// 196.074 us; speedup vs baseline: 1.9386x; 1.9386x over previous
//
#include <hip/hip_runtime.h>
#include <math.h>

#define BB 4
#define CC 256
#define DD 32
#define NN 4096

typedef __attribute__((ext_vector_type(8))) short short8;
typedef __attribute__((ext_vector_type(4))) float floatx4;
typedef __attribute__((ext_vector_type(4))) int intx4;

#define SCALEF (0.17677669529663687f * 1.4426950408889634f)  // 1/sqrt(32)*log2(e)

// float -> bf16 round-to-nearest-even
__device__ __forceinline__ ushort f2bf(float f) {
    unsigned int u = __builtin_bit_cast(unsigned int, f);
    u += 0x7FFFu + ((u >> 16) & 1u);
    return (ushort)(u >> 16);
}
// pack two floats' bf16 truncations into one dword with a single v_perm_b32
__device__ __forceinline__ int pk_trunc(float a, float b) {
    return (int)__builtin_amdgcn_perm(__builtin_bit_cast(unsigned, b),
                                      __builtin_bit_cast(unsigned, a),
                                      0x07060302u);
}
__device__ __forceinline__ float fast_exp2(float x) {
#if __has_builtin(__builtin_amdgcn_exp2f)
    return __builtin_amdgcn_exp2f(x);
#else
    return exp2f(x);
#endif
}

// ---------------------------------------------------------------------------
// Kernel 0: fused prep — (a) first 144 linearized blocks convert weights to
// bf16: Wall[320][256] = [Wq*SCALEF ; Wk ; Wv], Wpb[256][256] = Wp;
// (b) all 1024 blocks transpose x (B,C,N) fp32 -> xT (B,N,C) bf16 via a
// 64x64 LDS tile.  Merging saves one dispatch + launch gap.
// ---------------------------------------------------------------------------
#define TP 66
__global__ __launch_bounds__(256) void prep_fused(
    const float* __restrict__ x,
    const float* __restrict__ Wq, const float* __restrict__ Wk,
    const float* __restrict__ Wv, const float* __restrict__ Wp,
    ushort* __restrict__ xT, ushort* __restrict__ Wall, ushort* __restrict__ Wpb)
{
    __shared__ ushort tile[64 * TP];
    const int t = threadIdx.x;

    // ---- weight conversion (first 144 blocks only) ----
    const int bid = (blockIdx.z * gridDim.y + blockIdx.y) * gridDim.x + blockIdx.x;
    if (bid < 144) {
        const int e = (bid * 256 + t) * 4;   // 576 rows x 256 cols
        const int row = e >> 8, col = e & 255;
        const float* src;
        float s = 1.0f;
        ushort* dst;
        int drow;
        if (row < 32)       { src = Wq + (size_t)row * CC;          s = SCALEF; dst = Wall; drow = row; }
        else if (row < 64)  { src = Wk + (size_t)(row - 32) * CC;   dst = Wall; drow = row; }
        else if (row < 320) { src = Wv + (size_t)(row - 64) * CC;   dst = Wall; drow = row; }
        else                { src = Wp + (size_t)(row - 320) * CC;  dst = Wpb;  drow = row - 320; }
        const floatx4 w = *(const floatx4*)(src + col);
        int2 d;
        d.x = pk_trunc(w[0] * s, w[1] * s);
        d.y = pk_trunc(w[2] * s, w[3] * s);
        *(int2*)(dst + (size_t)drow * CC + col) = d;
    }

    // ---- x transpose tile ----
    const int b = blockIdx.z;
    const int c0 = blockIdx.y * 64;
    const int n0 = blockIdx.x * 64;
    const int cl = (t >> 4) * 4;   // 0..60, 4 c-rows per thread
    const int nl = (t & 15) * 4;   // 0..60, 4 n-cols per thread

    const float* src = x + ((size_t)b * CC + c0 + cl) * NN + n0 + nl;
    floatx4 v[4];
    #pragma unroll
    for (int i = 0; i < 4; ++i) v[i] = *(const floatx4*)(src + (size_t)i * NN);

    #pragma unroll
    for (int j = 0; j < 4; ++j) {
        *(int*)&tile[(nl + j) * TP + cl]     = pk_trunc(v[0][j], v[1][j]);
        *(int*)&tile[(nl + j) * TP + cl + 2] = pk_trunc(v[2][j], v[3][j]);
    }
    __syncthreads();

    const int nr = t >> 2;            // 0..63
    const int coff = (t & 3) * 16;    // 0,16,32,48
    int r[8];
    #pragma unroll
    for (int u = 0; u < 8; ++u) r[u] = *(const int*)&tile[nr * TP + coff + u * 2];
    ushort* dst = xT + ((size_t)b * NN + n0 + nr) * CC + c0 + coff;
    intx4 o0 = {r[0], r[1], r[2], r[3]};
    intx4 o1 = {r[4], r[5], r[6], r[7]};
    *(intx4*)dst = o0;
    *(intx4*)(dst + 8) = o1;
}

// ---------------------------------------------------------------------------
// Kernel 1: MFMA QKV projection v2 — pure bf16 short8 loads (A from Wall,
// B from xT), 4 loads + 4 MFMA per k-step.  (R1-verbatim, passing.)
// ---------------------------------------------------------------------------
__global__ __launch_bounds__(256) void qkv_mfma(
    const ushort* __restrict__ xT, const ushort* __restrict__ Wall,
    const float* __restrict__ bq, const float* __restrict__ bk,
    const float* __restrict__ bv,
    ushort* __restrict__ qb, ushort* __restrict__ kb, ushort* __restrict__ vb)
{
    const int t = threadIdx.x;
    const int wave = t >> 6;
    const int lane = t & 63;
    const int l15 = lane & 15, qd = lane >> 4;
    const int b = blockIdx.z, mt = blockIdx.y;   // mt 0..9
    const int n0 = blockIdx.x * 128 + wave * 32;

    const ushort* arow = Wall + (size_t)(mt * 32 + l15) * CC + qd * 8;
    const ushort* brow = xT + ((size_t)b * NN + n0 + l15) * CC + qd * 8;

    floatx4 z = {0.f, 0.f, 0.f, 0.f};
    floatx4 acc[2][2];
    acc[0][0] = z; acc[0][1] = z; acc[1][0] = z; acc[1][1] = z;

    #pragma unroll
    for (int k0 = 0; k0 < CC; k0 += 32) {
        short8 af[2], bfr[2];
        af[0]  = *(const short8*)(arow + k0);
        af[1]  = *(const short8*)(arow + 16 * CC + k0);
        bfr[0] = *(const short8*)(brow + k0);
        bfr[1] = *(const short8*)(brow + 16 * CC + k0);
        #pragma unroll
        for (int fm = 0; fm < 2; ++fm)
            #pragma unroll
            for (int fn = 0; fn < 2; ++fn)
                acc[fm][fn] = __builtin_amdgcn_mfma_f32_16x16x32_bf16(af[fm], bfr[fn], acc[fm][fn], 0, 0, 0);
    }

    #pragma unroll
    for (int fm = 0; fm < 2; ++fm) {
        const int o0 = fm * 16 + qd * 4;
        if (mt == 0) {
            const floatx4 bb = *(const floatx4*)(bq + o0);
            #pragma unroll
            for (int fn = 0; fn < 2; ++fn) {
                ushort4 h;
                h.x = f2bf(acc[fm][fn][0] + bb[0] * SCALEF);
                h.y = f2bf(acc[fm][fn][1] + bb[1] * SCALEF);
                h.z = f2bf(acc[fm][fn][2] + bb[2] * SCALEF);
                h.w = f2bf(acc[fm][fn][3] + bb[3] * SCALEF);
                *(ushort4*)(qb + ((size_t)b * NN + n0 + fn * 16 + l15) * DD + o0) = h;
            }
        } else if (mt == 1) {
            const floatx4 bb = *(const floatx4*)(bk + o0);
            #pragma unroll
            for (int fn = 0; fn < 2; ++fn) {
                ushort4 h;
                h.x = f2bf(acc[fm][fn][0] + bb[0]);
                h.y = f2bf(acc[fm][fn][1] + bb[1]);
                h.z = f2bf(acc[fm][fn][2] + bb[2]);
                h.w = f2bf(acc[fm][fn][3] + bb[3]);
                *(ushort4*)(kb + ((size_t)b * NN + n0 + fn * 16 + l15) * DD + o0) = h;
            }
        } else {
            const int oc = (mt - 2) * 32 + o0;
            const floatx4 bb = *(const floatx4*)(bv + oc);
            #pragma unroll
            for (int r = 0; r < 4; ++r)
                #pragma unroll
                for (int fn = 0; fn < 2; ++fn)
                    vb[((size_t)b * CC + oc + r) * NN + n0 + fn * 16 + l15] = f2bf(acc[fm][fn][r] + bb[r]);
        }
    }
}

// ---------------------------------------------------------------------------
// Kernel 2: MFMA flash attention — R6 structure VERBATIM, with the channel
// tile widened 64 -> 128 (grid z 4 -> 2).  This halves the redundant QK^T +
// exp2 + shfl work (P was recomputed once per c-group) while keeping every
// verified index mapping bit-identical; only the ct extent doubles (vf[8],
// acc[4][8], red[2][8192], epilogue ct 0..7).  setprio(1) wraps the PV MFMA
// cluster (T5).  Block = 4 waves = 4 key-quarters of one (64-q tile, 128-ch
// group); partial O/l additive; 3-barrier LDS tree.  Grid (8,32,2) = 512
// blocks = 2/CU (LDS 66KB, VGPR ~240 -> 2 waves/SIMD).
// ---------------------------------------------------------------------------
__global__ __launch_bounds__(256, 2) void attn_mfma(
    const ushort* __restrict__ qb, const ushort* __restrict__ kb,
    const ushort* __restrict__ vb, ushort* __restrict__ aoT)
{
    __shared__ float red[2][8192];   // [slot][((f*8+ct)*4+r)*64 + lane]
    __shared__ float lred[2][64];    // [slot][f*16 + q]

    const int t = threadIdx.x;
    const int kh = t >> 6;               // key-quarter 0..3
    const int lane = t & 63;
    const int l15 = lane & 15;
    const int qd = lane >> 4;
    const int slot = blockIdx.x;         // ~XCD id (round-robin heuristic)
    const int b = slot >> 1;             // 2 XCDs per batch
    const int qt = (slot & 1) * 32 + blockIdx.y;
    const int q0 = qt * 64;
    const int c0 = blockIdx.z * 128;

    const ushort* krow = kb + ((size_t)b * NN + kh * 1024 + l15) * DD + qd * 8;
    const ushort* vrow = vb + ((size_t)b * CC + c0 + l15) * (size_t)NN + kh * 1024 + qd * 8;

    short8 qf[4];
    #pragma unroll
    for (int f = 0; f < 4; ++f)
        qf[f] = *(const short8*)(qb + ((size_t)b * NN + q0 + f * 16 + l15) * DD + qd * 8);

    const short8 ones = {0x3F80, 0x3F80, 0x3F80, 0x3F80, 0x3F80, 0x3F80, 0x3F80, 0x3F80};

    floatx4 z = {0.f, 0.f, 0.f, 0.f};
    floatx4 acc[4][8];   // [qfrag][chfrag]
    floatx4 accl[4];
    #pragma unroll
    for (int f = 0; f < 4; ++f) {
        accl[f] = z;
        #pragma unroll
        for (int c = 0; c < 8; ++c) acc[f][c] = z;
    }

    const int base  = (qd & 1) * 32 + l15;   // proven transpose lane mapping
    const int base2 = base + 16;
    const bool hi = (lane >= 32);

    for (int kt = 0; kt < 32; ++kt) {
        short8 kf0 = *(const short8*)(krow);
        short8 kf1 = *(const short8*)(krow + 16 * DD);
        short8 vf[8];
        #pragma unroll
        for (int ct = 0; ct < 8; ++ct)
            vf[ct] = *(const short8*)(vrow + (size_t)ct * 16 * NN);
        krow += 32 * DD;
        vrow += 32;

        short8 pt[4];
        #pragma unroll
        for (int f = 0; f < 4; ++f) {
            floatx4 s0 = __builtin_amdgcn_mfma_f32_16x16x32_bf16(kf0, qf[f], z, 0, 0, 0);
            floatx4 s1 = __builtin_amdgcn_mfma_f32_16x16x32_bf16(kf1, qf[f], z, 0, 0, 0);

            float e00 = fast_exp2(s0[0]), e01 = fast_exp2(s0[1]);
            float e02 = fast_exp2(s0[2]), e03 = fast_exp2(s0[3]);
            float e10 = fast_exp2(s1[0]), e11 = fast_exp2(s1[1]);
            float e12 = fast_exp2(s1[2]), e13 = fast_exp2(s1[3]);

            int A0 = pk_trunc(e00, e01);
            int A1 = pk_trunc(e02, e03);
            int B0 = pk_trunc(e10, e11);
            int B1 = pk_trunc(e12, e13);

            int w0a = __shfl(A0, base);  int w0b = __shfl(B0, base);
            int w1a = __shfl(A1, base);  int w1b = __shfl(B1, base);
            int w2a = __shfl(A0, base2); int w2b = __shfl(B0, base2);
            int w3a = __shfl(A1, base2); int w3b = __shfl(B1, base2);

            intx4 ptd;
            ptd[0] = hi ? w0b : w0a;
            ptd[1] = hi ? w1b : w1a;
            ptd[2] = hi ? w2b : w2a;
            ptd[3] = hi ? w3b : w3a;
            pt[f] = __builtin_bit_cast(short8, ptd);
        }

        #pragma unroll
        for (int f = 0; f < 4; ++f)
            accl[f] = __builtin_amdgcn_mfma_f32_16x16x32_bf16(ones, pt[f], accl[f], 0, 0, 0);

        __builtin_amdgcn_s_setprio(1);
        #pragma unroll
        for (int ct = 0; ct < 8; ++ct)
            #pragma unroll
            for (int f = 0; f < 4; ++f)
                acc[f][ct] = __builtin_amdgcn_mfma_f32_16x16x32_bf16(vf[ct], pt[f], acc[f][ct], 0, 0, 0);
        __builtin_amdgcn_s_setprio(0);
    }

    float lsum[4];
    #pragma unroll
    for (int f = 0; f < 4; ++f) lsum[f] = accl[f][0];

    // ---- reduction tree over key-quarters: (0+=1, 2+=3), then 0+=2 ----
    if (kh & 1) {
        const int s = kh >> 1;
        #pragma unroll
        for (int f = 0; f < 4; ++f)
            #pragma unroll
            for (int ct = 0; ct < 8; ++ct)
                #pragma unroll
                for (int r = 0; r < 4; ++r)
                    red[s][((f * 8 + ct) * 4 + r) * 64 + lane] = acc[f][ct][r];
        if (qd == 0)
            #pragma unroll
            for (int f = 0; f < 4; ++f) lred[s][f * 16 + l15] = lsum[f];
    }
    __syncthreads();
    if (!(kh & 1)) {
        const int s = kh >> 1;
        #pragma unroll
        for (int f = 0; f < 4; ++f) {
            #pragma unroll
            for (int ct = 0; ct < 8; ++ct)
                #pragma unroll
                for (int r = 0; r < 4; ++r)
                    acc[f][ct][r] += red[s][((f * 8 + ct) * 4 + r) * 64 + lane];
            lsum[f] += lred[s][f * 16 + l15];
        }
    }
    __syncthreads();
    if (kh == 2) {
        #pragma unroll
        for (int f = 0; f < 4; ++f)
            #pragma unroll
            for (int ct = 0; ct < 8; ++ct)
                #pragma unroll
                for (int r = 0; r < 4; ++r)
                    red[0][((f * 8 + ct) * 4 + r) * 64 + lane] = acc[f][ct][r];
        if (qd == 0)
            #pragma unroll
            for (int f = 0; f < 4; ++f) lred[0][f * 16 + l15] = lsum[f];
    }
    __syncthreads();
    if (kh == 0) {
        #pragma unroll
        for (int f = 0; f < 4; ++f) {
            #pragma unroll
            for (int ct = 0; ct < 8; ++ct)
                #pragma unroll
                for (int r = 0; r < 4; ++r)
                    acc[f][ct][r] += red[0][((f * 8 + ct) * 4 + r) * 64 + lane];
            lsum[f] += lred[0][f * 16 + l15];
        }
        #pragma unroll
        for (int f = 0; f < 4; ++f) {
            const float inv = 1.0f / lsum[f];
            ushort* dst = aoT + ((size_t)b * NN + q0 + f * 16 + l15) * CC + c0 + qd * 4;
            #pragma unroll
            for (int ct = 0; ct < 8; ++ct) {
                ushort4 h;
                h.x = f2bf(acc[f][ct][0] * inv);
                h.y = f2bf(acc[f][ct][1] * inv);
                h.z = f2bf(acc[f][ct][2] * inv);
                h.w = f2bf(acc[f][ct][3] * inv);
                *(ushort4*)(dst + ct * 16) = h;
            }
        }
    }
}

// ---------------------------------------------------------------------------
// Kernel 3: MFMA output projection + residual v2.  (R1-verbatim, passing.)
// ---------------------------------------------------------------------------
__global__ __launch_bounds__(256) void proj_mfma(
    const ushort* __restrict__ aoT, const ushort* __restrict__ Wpb,
    const float* __restrict__ bp, const float* __restrict__ x,
    const float* __restrict__ gamma, float* __restrict__ out)
{
    const int t = threadIdx.x;
    const int wave = t >> 6;
    const int lane = t & 63;
    const int l15 = lane & 15;
    const int qd = lane >> 4;
    const int b = blockIdx.z;
    const int m0 = blockIdx.y * 32;
    const int n0 = blockIdx.x * 128 + wave * 32;

    floatx4 z = {0.f, 0.f, 0.f, 0.f};
    floatx4 acc[2][2];   // [fm][fn]
    acc[0][0] = z; acc[0][1] = z; acc[1][0] = z; acc[1][1] = z;

    const ushort* arow = aoT + ((size_t)b * NN + n0 + l15) * CC + qd * 8;
    const ushort* wrow = Wpb + (size_t)(m0 + l15) * CC + qd * 8;

    #pragma unroll
    for (int k0 = 0; k0 < CC; k0 += 32) {
        short8 af[2], bfr[2];
        af[0]  = *(const short8*)(wrow + k0);
        af[1]  = *(const short8*)(wrow + 16 * CC + k0);
        bfr[0] = *(const short8*)(arow + k0);
        bfr[1] = *(const short8*)(arow + 16 * CC + k0);
        #pragma unroll
        for (int fm = 0; fm < 2; ++fm)
            #pragma unroll
            for (int fn = 0; fn < 2; ++fn)
                acc[fm][fn] = __builtin_amdgcn_mfma_f32_16x16x32_bf16(af[fm], bfr[fn], acc[fm][fn], 0, 0, 0);
    }

    const float g = gamma[0];
    #pragma unroll
    for (int fm = 0; fm < 2; ++fm) {
        #pragma unroll
        for (int r = 0; r < 4; ++r) {
            int m = m0 + fm * 16 + qd * 4 + r;
            float bpv = bp[m];
            #pragma unroll
            for (int fn = 0; fn < 2; ++fn) {
                size_t addr = ((size_t)b * CC + m) * NN + n0 + fn * 16 + l15;
                out[addr] = fmaf(g, acc[fm][fn][r] + bpv, x[addr]);
            }
        }
    }
}

extern "C" void kernel_launch(void* const* d_in, const int* in_sizes, int n_in,
                              void* d_out, int out_size, void* d_ws, size_t ws_size,
                              hipStream_t stream)
{
    const float* x     = (const float*)d_in[0];
    const float* Wq    = (const float*)d_in[1];
    const float* bq    = (const float*)d_in[2];
    const float* Wk    = (const float*)d_in[3];
    const float* bk    = (const float*)d_in[4];
    const float* Wv    = (const float*)d_in[5];
    const float* bv    = (const float*)d_in[6];
    const float* Wp    = (const float*)d_in[7];
    const float* bp    = (const float*)d_in[8];
    const float* gamma = (const float*)d_in[9];
    float* out = (float*)d_out;

    ushort* qbw  = (ushort*)d_ws;                        // B*N*32  bf16 = 1 MB
    ushort* kbw  = qbw + (size_t)BB * NN * DD;           // B*N*32  bf16 = 1 MB
    ushort* vbw  = kbw + (size_t)BB * NN * DD;           // B*C*N   bf16 = 8 MB
    ushort* xaoT = vbw + (size_t)BB * CC * NN;           // xT during qkv, aoT after attn (8 MB, aliased)
    ushort* Wall = xaoT + (size_t)BB * NN * CC;          // 320*256 bf16 = 160 KB
    ushort* Wpb  = Wall + (size_t)320 * CC;              // 256*256 bf16 = 128 KB

    prep_fused<<<dim3(NN / 64, CC / 64, BB), 256, 0, stream>>>(x, Wq, Wk, Wv, Wp, xaoT, Wall, Wpb);
    qkv_mfma<<<dim3(NN / 128, 10, BB), 256, 0, stream>>>(xaoT, Wall, bq, bk, bv, qbw, kbw, vbw);
    attn_mfma<<<dim3(8, 32, 2), 256, 0, stream>>>(qbw, kbw, vbw, xaoT);
    proj_mfma<<<dim3(NN / 128, CC / 32, BB), 256, 0, stream>>>(xaoT, Wpb, bp, x, gamma, out);
}